// Round 7
// baseline (94.916 us; speedup 1.0000x reference)
//
#include <hip/hip_runtime.h>

// Chamfer distance, B=16 clouds x N=4096 x D=3, fp32, via bf16-split MFMA.
// S_ij = d(x_i, y_j) computed by ONE v_mfma_f32_32x32x16_bf16 dot (K=16):
//   A_i = [xh0..2, xl0..2, xh0..2, x2h, x2l, 1, 1, xl0..2]
//   B_j = [-2yh0..2, -2yh0..2, -2yl0..2, 1, 1, y2h, y2l, -2yl0..2]
//   sum_k A_ik B_jk = x^2 + y^2 - 2(xh+xl).(yh+yl)  (abs err <~7e-4)
// History: R8 96.0 (3 kernels). R9/R10 device-atomics+fences 137 REGRESSION.
//   R11 +min3 98.5 NEUTRAL. R12 launch_bounds(256,5) FAILED (unschedulable).
//   R13 fused prep+LDS 100.8 NEUTRAL. R14 direction-split row-min-only:
//   94.5 total, cd_fused=43us VISIBLE: VALUBusy 69%, Mfma 15%, HBM 2%.
//   Diagnosis: in-kernel bf16-split dequant (~140 ops/pt, re-done 64x per
//   cloud) is ~60% of VALU issue; direction split doubled it.
// R15: split ONCE in cd_prep (A-format rows row-major for per-lane A-frag
//   loads; B-format rows PLANE-SEPARATED [cloud][stage][khalf][pt] so the
//   LDS stage image is linear). cd_mfma stages via global_load_lds width=16
//   (4 issues/thread/stage, wave-uniform dst + lane*16, per-lane src),
//   double-buffered 2x16KB, inner loop = contiguous ds_read_b128 (stride-16
//   per half-group: conflict-free, no swizzle) + 2 MFMA + 16 v_min3.
//   Row-min-only epilogue from R14. Workspace 8MB. 2 launches.

namespace {

constexpr int kB = 16;
constexpr int kN = 4096;
constexpr int kPlane = kB * kN;
constexpr int kStage = 512;               // points per LDS stage
constexpr int kNS = kN / kStage;          // 8 stages
constexpr float kScale = 1.0f / (float)(kB * kN);

typedef short bf16x8 __attribute__((ext_vector_type(8)));
typedef float f32x16 __attribute__((ext_vector_type(16)));
typedef unsigned short u16;

__device__ inline u16 bf16_rn(float f) {
  union { float f; unsigned u; } v; v.f = f;
  unsigned r = v.u + 0x7fffu + ((v.u >> 16) & 1u);
  return (u16)(r >> 16);
}
__device__ inline float bf16_f(u16 h) {
  union { unsigned u; float f; } v; v.u = (unsigned)h << 16;
  return v.f;
}
__device__ inline unsigned pk2(u16 lo, u16 hi) {
  return (unsigned)lo | ((unsigned)hi << 16);
}

__global__ void init_out(float* out) { out[0] = 0.0f; }

// One thread per point p: build A-format row (row-major, 32B at p*32) and
// B-format row (plane-separated: [cloud][stg][h][pl] 16B chunks) for BOTH
// pred and targ. Also zeroes out[0].
__global__ __launch_bounds__(256) void cd_prep(
    const float* __restrict__ pred, const float* __restrict__ targ,
    u16* __restrict__ Apred, u16* __restrict__ Atarg,
    u16* __restrict__ Bpred, u16* __restrict__ Btarg,
    float* __restrict__ out) {
  const int p = blockIdx.x * 256 + threadIdx.x;   // 0..kPlane-1
  if (p == 0) out[0] = 0.0f;
  const int cloud = p >> 12, q = p & (kN - 1);
  const int stg = q >> 9, pl = q & (kStage - 1);
  // u16 offsets: B plane-sep = cloud*65536 + stg*8192 + h*4096 + pl*8
  const size_t boff = (size_t)cloud * 65536 + (size_t)stg * 8192 + (size_t)pl * 8;
  const u16 one = 0x3F80;

  const float* srcs[2] = {pred, targ};
  u16* adsts[2] = {Apred, Atarg};
  u16* bdsts[2] = {Bpred, Btarg};
#pragma unroll
  for (int which = 0; which < 2; ++which) {
    const float a = srcs[which][3 * p], c = srcs[which][3 * p + 1],
                d = srcs[which][3 * p + 2];
    const u16 ah = bf16_rn(a), ch = bf16_rn(c), dh = bf16_rn(d);
    const u16 al = bf16_rn(a - bf16_f(ah));
    const u16 cl = bf16_rn(c - bf16_f(ch));
    const u16 dl = bf16_rn(d - bf16_f(dh));
    const float s2 = fmaf(a, a, fmaf(c, c, d * d));
    const u16 s2h = bf16_rn(s2);
    const u16 s2l = bf16_rn(s2 - bf16_f(s2h));
    {  // A row, k: 0-2 xh, 3-5 xl, 6-8 xh, 9 x2h, 10 x2l, 11 1, 12 1, 13-15 xl
      uint4 w0, w1;
      w0.x = pk2(ah, ch); w0.y = pk2(dh, al); w0.z = pk2(cl, dl); w0.w = pk2(ah, ch);
      w1.x = pk2(dh, s2h); w1.y = pk2(s2l, one); w1.z = pk2(one, al); w1.w = pk2(cl, dl);
      uint4* dst = reinterpret_cast<uint4*>(adsts[which] + (size_t)p * 16);
      dst[0] = w0; dst[1] = w1;
    }
    {  // B row, k: 0-2 -2yh, 3-5 -2yh, 6-8 -2yl, 9 1, 10 1, 11 y2h, 12 y2l, 13-15 -2yl
      const u16 nah = bf16_rn(-2.0f * bf16_f(ah));   // exact scale by -2
      const u16 nch = bf16_rn(-2.0f * bf16_f(ch));
      const u16 ndh = bf16_rn(-2.0f * bf16_f(dh));
      const u16 nal = bf16_rn(-2.0f * bf16_f(al));
      const u16 ncl = bf16_rn(-2.0f * bf16_f(cl));
      const u16 ndl = bf16_rn(-2.0f * bf16_f(dl));
      uint4 w0, w1;
      w0.x = pk2(nah, nch); w0.y = pk2(ndh, nah); w0.z = pk2(nch, ndh); w0.w = pk2(nal, ncl);
      w1.x = pk2(ndl, one); w1.y = pk2(one, s2h); w1.z = pk2(s2l, nal); w1.w = pk2(ncl, ndl);
      *reinterpret_cast<uint4*>(bdsts[which] + boff) = w0;
      *reinterpret_cast<uint4*>(bdsts[which] + boff + 4096) = w1;
    }
  }
}

// One block = 4 waves x 32 rows = 128 rows of X (cloud, chunk); scans all kN
// opposite points staged through double-buffered LDS via global_load_lds.
// C/D layout (32x32x16): col=lane&31, row=(reg&3)+8*(reg>>2)+4*(lane>>5).
// Row-min only; 32-lane butterfly completes min over j; block-sum -> atomicAdd.
__global__ __launch_bounds__(256) void cd_mfma(
    const u16* __restrict__ Apred, const u16* __restrict__ Atarg,
    const u16* __restrict__ Bpred, const u16* __restrict__ Btarg,
    float* __restrict__ out) {
  __shared__ uint4 Blds4[2048];   // 32 KB: double-buffered stage (2 x 16 KB)
  __shared__ float wsum[4];

  const int t = threadIdx.x;
  const int w = t >> 6, lane = t & 63;
  const int half = lane >> 5, l31 = lane & 31;
  const int chunk = blockIdx.x;      // 0..31 -> 128 rows per block
  const int cloud = blockIdx.y;      // 0..15
  const int dir = blockIdx.z;        // 0: pred rows vs targ; 1: swapped
  const u16* __restrict__ A = dir ? Atarg : Apred;
  const u16* __restrict__ B = dir ? Bpred : Btarg;

  // ---- A fragment: one 16B load (lane l31 -> row, half -> k-half) ----
  const int arow = cloud * kN + chunk * 128 + w * 32 + l31;
  union { uint4 u; bf16x8 v; } afu;
  afu.u = *reinterpret_cast<const uint4*>(A + (size_t)arow * 16 + half * 8);
  const bf16x8 afrag = afu.v;

  // ---- staging setup: linear copy, 4 x global_load_lds(16B) per thread ----
  const char* bcloud = (const char*)B + (size_t)cloud * 131072;  // 128KB/cloud
  char* ldsbase = (char*)Blds4;
  // per-issue: dst chunk s = (w*4+i)*64 + lane (linear); src = s*16 + st*16384
#define STAGE(st, buf)                                                        \
  {                                                                           \
    const char* _src = bcloud + (size_t)(st) * 16384;                         \
    char* _dst = ldsbase + (buf) * 16384;                                     \
    _Pragma("unroll")                                                         \
    for (int i = 0; i < 4; ++i) {                                             \
      __builtin_amdgcn_global_load_lds(                                       \
          (const __attribute__((address_space(1))) void*)(_src +              \
              ((w * 4 + i) * 64 + lane) * 16),                                \
          (__attribute__((address_space(3))) void*)(_dst + (w * 4 + i) * 1024),\
          16, 0, 0);                                                          \
    }                                                                         \
  }

  f32x16 zacc;
#pragma unroll
  for (int r = 0; r < 16; ++r) zacc[r] = 0.0f;
  float rmin[16];
#pragma unroll
  for (int r = 0; r < 16; ++r) rmin[r] = 1e30f;

  STAGE(0, 0);
  __syncthreads();   // drains vmcnt -> buf0 ready

  for (int st = 0; st < kNS; ++st) {
    if (st < kNS - 1) STAGE(st + 1, (st + 1) & 1);
    // read base: buffer + k-half plane (8KB) + own column chunk
    const char* blc = ldsbase + (st & 1) * 16384 + half * 8192 + l31 * 16;
#pragma unroll
    for (int jt = 0; jt < kStage / 64; ++jt) {   // 8 iters, 64 j each
      union { uint4 u; bf16x8 v; } B0, B1;
      B0.u = *reinterpret_cast<const uint4*>(blc + jt * 1024);
      B1.u = *reinterpret_cast<const uint4*>(blc + jt * 1024 + 512);
      const f32x16 s0 =
          __builtin_amdgcn_mfma_f32_32x32x16_bf16(afrag, B0.v, zacc, 0, 0, 0);
      const f32x16 s1 =
          __builtin_amdgcn_mfma_f32_32x32x16_bf16(afrag, B1.v, zacc, 0, 0, 0);
#pragma unroll
      for (int r = 0; r < 16; ++r)
        asm("v_min3_f32 %0, %0, %1, %2"
            : "+v"(rmin[r]) : "v"(s0[r]), "v"(s1[r]));
    }
    __syncthreads();   // next-stage loads visible; compute done before overwrite
  }
#undef STAGE

  // Complete row-mins: butterfly across the 32 lanes of each half.
#pragma unroll
  for (int st = 1; st < 32; st <<= 1) {
#pragma unroll
    for (int r = 0; r < 16; ++r)
      rmin[r] = fminf(rmin[r], __shfl_xor(rmin[r], st, 64));
  }
  // Halves partition the 32 rows: rows {(r&3)+8*(r>>2)+4*half}.
  float s = 0.0f;
#pragma unroll
  for (int r = 0; r < 16; ++r) s += rmin[r];
  s = (l31 == 0) ? s : 0.0f;        // one contributor per half
  s += __shfl_down(s, 32, 64);      // lane 0 <- both halves
  if (lane == 0) wsum[w] = s;
  __syncthreads();
  if (t == 0)
    atomicAdd(out, (wsum[0] + wsum[1] + wsum[2] + wsum[3]) * kScale);
}

// ---------- fallback (small ws): R5-style pk_fma direct kernel ----------
template <int KX>
__global__ __launch_bounds__(256) void chamfer_direct(
    const float* __restrict__ pred, const float* __restrict__ targ,
    float* __restrict__ out) {
  __shared__ float4 tA[128], tB[128];
  const int t = threadIdx.x;
  const int xb = blockIdx.x, b = blockIdx.y, dir = blockIdx.z;
  const float* __restrict__ X = dir ? targ : pred;
  const float* __restrict__ Y = dir ? pred : targ;
  float2 xx2[KX], xy2[KX], xz2[KX];
  float x2[KX], mn[KX];
  const int ibase = b * kN + xb * (256 * KX) + t;
#pragma unroll
  for (int k = 0; k < KX; ++k) {
    const int i = ibase + k * 256;
    const float a = X[3 * i], c = X[3 * i + 1], d = X[3 * i + 2];
    x2[k] = fmaf(a, a, fmaf(c, c, d * d));
    xx2[k] = make_float2(-2.0f * a, -2.0f * a);
    xy2[k] = make_float2(-2.0f * c, -2.0f * c);
    xz2[k] = make_float2(-2.0f * d, -2.0f * d);
    mn[k] = 1e30f;
  }
  for (int t0 = 0; t0 < kN; t0 += 256) {
    __syncthreads();
    if (t < 128) {
      const int j0 = 3 * (b * kN + t0 + 2 * t);
      const float a0 = Y[j0], c0 = Y[j0 + 1], d0 = Y[j0 + 2];
      const float a1 = Y[j0 + 3], c1 = Y[j0 + 4], d1 = Y[j0 + 5];
      tA[t] = make_float4(a0, a1, c0, c1);
      tB[t] = make_float4(d0, d1, fmaf(a0, a0, fmaf(c0, c0, d0 * d0)),
                          fmaf(a1, a1, fmaf(c1, c1, d1 * d1)));
    }
    __syncthreads();
    for (int jj = 0; jj < 128; ++jj) {
      const float4 qa = tA[jj], qb = tB[jj];
      const float2 qx = make_float2(qa.x, qa.y), qy = make_float2(qa.z, qa.w);
      const float2 qz = make_float2(qb.x, qb.y), qw = make_float2(qb.z, qb.w);
#pragma unroll
      for (int k = 0; k < KX; ++k) {
        float2 acc;
        asm("v_pk_fma_f32 %0, %1, %2, %3\n\t"
            "v_pk_fma_f32 %0, %4, %5, %0\n\t"
            "v_pk_fma_f32 %0, %6, %7, %0"
            : "=&v"(acc)
            : "v"(xz2[k]), "v"(qz), "v"(qw), "v"(xy2[k]), "v"(qy),
              "v"(xx2[k]), "v"(qx));
        asm("v_min3_f32 %0, %0, %1, %2" : "+v"(mn[k]) : "v"(acc.x), "v"(acc.y));
      }
    }
  }
  float s = 0.0f;
#pragma unroll
  for (int k = 0; k < KX; ++k) s += x2[k] + mn[k];
  for (int o = 32; o > 0; o >>= 1) s += __shfl_down(s, o, 64);
  __shared__ float wsum[4];
  const int lane = t & 63, wv = t >> 6;
  if (lane == 0) wsum[wv] = s;
  __syncthreads();
  if (t == 0)
    atomicAdd(out, (wsum[0] + wsum[1] + wsum[2] + wsum[3]) * kScale);
}

}  // namespace

extern "C" void kernel_launch(void* const* d_in, const int* in_sizes, int n_in,
                              void* d_out, int out_size, void* d_ws,
                              size_t ws_size, hipStream_t stream) {
  const float* pred = (const float*)d_in[0];
  const float* targ = (const float*)d_in[1];
  float* out = (float*)d_out;

  const size_t needOne = (size_t)kPlane * 16 * sizeof(u16);   // 2 MB each
  if (ws_size >= 4 * needOne) {                               // 8 MB
    u16* Apred = (u16*)d_ws;
    u16* Atarg = (u16*)((char*)d_ws + needOne);
    u16* Bpred = (u16*)((char*)d_ws + 2 * needOne);
    u16* Btarg = (u16*)((char*)d_ws + 3 * needOne);
    cd_prep<<<dim3(kPlane / 256), 256, 0, stream>>>(pred, targ, Apred, Atarg,
                                                    Bpred, Btarg, out);
    cd_mfma<<<dim3(32, kB, 2), 256, 0, stream>>>(Apred, Atarg, Bpred, Btarg,
                                                 out);
  } else {
    init_out<<<dim3(1), dim3(1), 0, stream>>>(out);
    constexpr int KX = 8;
    dim3 grid(kN / (256 * KX), kB, 2);
    chamfer_direct<KX><<<grid, 256, 0, stream>>>(pred, targ, out);
  }
}